// Round 5
// baseline (1725.204 us; speedup 1.0000x reference)
//
#include <hip/hip_runtime.h>

// VectorQuantizer: z [16,256,1024] fp32, emb [8192,256] fp32.
// out (FP32): [ z_q 4194304 | loss 1 | idx 16384 ]
// Emulates np fp32 ref: d = fl(fl(s_z[m]+s_e[n]) - 2*p[m,n]), argmin (lowest-index ties).
// s_z/s_e replicate numpy scalar pairwise_sum bit-exactly; p via fp32 GEMM (pass 1,
// top-2 per row) + fp64 recompute of the two candidates (pass 2).

#define C_    256
#define T_    1024
#define M_    16384
#define N_    8192
#define TM    64
#define TN    64
#define TK    32

#define OUT_ZQ   0
#define OUT_LOSS 4194304
#define OUT_IDX  4194305

// ws layout (4-byte units)
#define WS_SZ    0          // s_z [16384] float
#define WS_SE    16384      // s_e [8192]  float
#define WS_I1    24576      // i1  [16384] int
#define WS_I2    40960      // i2  [16384] int
#define WS_WIDX  57344      // winner idx [16384] int
#define WS_PART  73728      // loss partials [256] float

// ---------------- K0: s_z, s_e — numpy pairwise_sum replication ----------------
// np: n=256 -> pw(a,128)+pw(a+128,128); pw(128): r[0..7]=a[0..7];
//     for i=8..120 step 8: r[j]+=a[i+j]; ((r0+r1)+(r2+r3))+((r4+r5)+(r6+r7))
__global__ __launch_bounds__(256) void vq_sums(const float* __restrict__ z,
                                               const float* __restrict__ emb,
                                               float* __restrict__ ws) {
    int gid = blockIdx.x * 256 + threadIdx.x;
    if (gid < M_) {
        int b = gid >> 10, t = gid & (T_ - 1);
        const float* zp = z + (size_t)b * C_ * T_ + t;      // stride T_ over c
        float blk[2];
#pragma unroll
        for (int h = 0; h < 2; ++h) {
            float r[8];
#pragma unroll
            for (int j = 0; j < 8; ++j) {
                float v = zp[(size_t)(h * 128 + j) * T_];
                r[j] = __fmul_rn(v, v);
            }
            for (int i = 8; i < 128; i += 8)
#pragma unroll
                for (int j = 0; j < 8; ++j) {
                    float v = zp[(size_t)(h * 128 + i + j) * T_];
                    r[j] = __fadd_rn(r[j], __fmul_rn(v, v));
                }
            blk[h] = __fadd_rn(__fadd_rn(__fadd_rn(r[0], r[1]), __fadd_rn(r[2], r[3])),
                               __fadd_rn(__fadd_rn(r[4], r[5]), __fadd_rn(r[6], r[7])));
        }
        ws[WS_SZ + gid] = __fadd_rn(blk[0], blk[1]);
    } else if (gid < M_ + N_) {
        int n = gid - M_;
        const float* ep = emb + (size_t)n * C_;
        float blk[2];
#pragma unroll
        for (int h = 0; h < 2; ++h) {
            float r[8];
#pragma unroll
            for (int j = 0; j < 8; ++j) {
                float v = ep[h * 128 + j];
                r[j] = __fmul_rn(v, v);
            }
            for (int i = 8; i < 128; i += 8)
#pragma unroll
                for (int j = 0; j < 8; ++j) {
                    float v = ep[h * 128 + i + j];
                    r[j] = __fadd_rn(r[j], __fmul_rn(v, v));
                }
            blk[h] = __fadd_rn(__fadd_rn(__fadd_rn(r[0], r[1]), __fadd_rn(r[2], r[3])),
                               __fadd_rn(__fadd_rn(r[4], r[5]), __fadd_rn(r[6], r[7])));
        }
        ws[WS_SE + n] = __fadd_rn(blk[0], blk[1]);
    }
}

// ---------------- K1: pass-1 GEMM + per-row top-2 candidates ----------------
// grid 256, block 256. Thread (tx,ty)=(tid&15,tid>>4) owns 4x4 micro-tile.
__global__ __launch_bounds__(256) void vq_pass1(
        const float* __restrict__ z,
        const float* __restrict__ emb,
        float* __restrict__ ws) {
    __shared__ float As[TK][TM + 4];
    __shared__ float Bs[TK][TN + 4];

    const float* s_z = ws + WS_SZ;
    const float* s_e = ws + WS_SE;
    int* i1ws = (int*)ws + WS_I1;
    int* i2ws = (int*)ws + WS_I2;

    const int tid = threadIdx.x;
    const int mt  = blockIdx.x;
    const int tx  = tid & 15, ty = tid >> 4;
    const int b   = mt >> 4;
    const int t0  = (mt << 6) & (T_ - 1);
    const float* zbase = z + (size_t)b * C_ * T_ + t0;

    const int a_k = tid >> 4;
    const int a_m = (tid & 15) << 2;
    const int b_j = tid >> 2;
    const int b_q = (tid & 3) << 3;

    const float4 sz4 = *(const float4*)(s_z + mt * TM + (ty << 2));
    const float szv[4] = {sz4.x, sz4.y, sz4.z, sz4.w};

    float v1[4], v2[4];
    int   i1[4], i2[4];
#pragma unroll
    for (int i = 0; i < 4; ++i) {
        v1[i] = INFINITY; v2[i] = INFINITY;
        i1[i] = 0x7FFFFFFF; i2[i] = 0x7FFFFFFF;
    }

    for (int nt = 0; nt < N_ / TN; ++nt) {
        const int n0 = nt * TN;
        float acc[4][4];
#pragma unroll
        for (int i = 0; i < 4; ++i)
#pragma unroll
            for (int j = 0; j < 4; ++j) acc[i][j] = 0.f;

        for (int kt = 0; kt < C_; kt += TK) {
            __syncthreads();
#pragma unroll
            for (int p = 0; p < 2; ++p) {
                int k = a_k + p * 16;
                float4 af = *(const float4*)(zbase + (size_t)(kt + k) * T_ + a_m);
                *(float4*)&As[k][a_m] = af;
            }
            {
                const float* ep = emb + (size_t)(n0 + b_j) * C_ + kt + b_q;
                float4 e0 = ((const float4*)ep)[0];
                float4 e1 = ((const float4*)ep)[1];
                Bs[b_q + 0][b_j] = e0.x; Bs[b_q + 1][b_j] = e0.y;
                Bs[b_q + 2][b_j] = e0.z; Bs[b_q + 3][b_j] = e0.w;
                Bs[b_q + 4][b_j] = e1.x; Bs[b_q + 5][b_j] = e1.y;
                Bs[b_q + 6][b_j] = e1.z; Bs[b_q + 7][b_j] = e1.w;
            }
            __syncthreads();
#pragma unroll
            for (int k = 0; k < TK; ++k) {
                const float4 a  = *(const float4*)&As[k][ty << 2];
                const float4 bv = *(const float4*)&Bs[k][tx << 2];
                acc[0][0] = fmaf(a.x, bv.x, acc[0][0]);
                acc[0][1] = fmaf(a.x, bv.y, acc[0][1]);
                acc[0][2] = fmaf(a.x, bv.z, acc[0][2]);
                acc[0][3] = fmaf(a.x, bv.w, acc[0][3]);
                acc[1][0] = fmaf(a.y, bv.x, acc[1][0]);
                acc[1][1] = fmaf(a.y, bv.y, acc[1][1]);
                acc[1][2] = fmaf(a.y, bv.z, acc[1][2]);
                acc[1][3] = fmaf(a.y, bv.w, acc[1][3]);
                acc[2][0] = fmaf(a.z, bv.x, acc[2][0]);
                acc[2][1] = fmaf(a.z, bv.y, acc[2][1]);
                acc[2][2] = fmaf(a.z, bv.z, acc[2][2]);
                acc[2][3] = fmaf(a.z, bv.w, acc[2][3]);
                acc[3][0] = fmaf(a.w, bv.x, acc[3][0]);
                acc[3][1] = fmaf(a.w, bv.y, acc[3][1]);
                acc[3][2] = fmaf(a.w, bv.z, acc[3][2]);
                acc[3][3] = fmaf(a.w, bv.w, acc[3][3]);
            }
        }
        // epilogue: ref-formula score, top-2 update (ascending n per thread)
        const float4 se4 = *(const float4*)(s_e + n0 + (tx << 2));
        const float sev[4] = {se4.x, se4.y, se4.z, se4.w};
#pragma unroll
        for (int j = 0; j < 4; ++j) {
            const int n = n0 + (tx << 2) + j;
#pragma unroll
            for (int i = 0; i < 4; ++i) {
                float A = __fadd_rn(szv[i], sev[j]);       // fl(s_z+s_e)
                float s = fmaf(-2.f, acc[i][j], A);        // fl(A-2p), 2p exact
                if (s < v1[i]) {
                    v2[i] = v1[i]; i2[i] = i1[i];
                    v1[i] = s;     i1[i] = n;
                } else if (s < v2[i]) {
                    v2[i] = s;     i2[i] = n;
                }
            }
        }
    }

    // cross-tx top-2 merge (16 lanes per row group), write candidates
#pragma unroll
    for (int i = 0; i < 4; ++i) {
        float a1 = v1[i], a2 = v2[i];
        int   x1 = i1[i], x2 = i2[i];
#pragma unroll
        for (int off = 8; off >= 1; off >>= 1) {
            float ov1 = __shfl_xor(a1, off, 64); int ox1 = __shfl_xor(x1, off, 64);
            float ov2 = __shfl_xor(a2, off, 64); int ox2 = __shfl_xor(x2, off, 64);
            bool alt = (ov1 < a1) || (ov1 == a1 && ox1 < x1);
            float w1v = alt ? ov1 : a1;  int w1i = alt ? ox1 : x1;
            float lv  = alt ? a1  : ov1; int li  = alt ? x1  : ox1;
            float wsv = alt ? ov2 : a2;  int wsi = alt ? ox2 : x2;
            bool sb = (lv < wsv) || (lv == wsv && li < wsi);
            a2 = sb ? lv : wsv; x2 = sb ? li : wsi;
            a1 = w1v; x1 = w1i;
        }
        if (tx == 0) {
            int m = mt * TM + (ty << 2) + i;
            i1ws[m] = x1;
            i2ws[m] = x2;
        }
    }
}

// ---------------- K2: pass-2 fixup (fp64 dots for 2 candidates) + idx out ----------------
// grid 64, block 256 (4 waves); each wave owns 64 consecutive rows.
__global__ __launch_bounds__(256) void vq_pass2(
        const float* __restrict__ z,
        const float* __restrict__ emb,
        float* __restrict__ ws,
        float* __restrict__ out) {
    const float* s_z = ws + WS_SZ;
    const float* s_e = ws + WS_SE;
    const int* i1ws = (const int*)ws + WS_I1;
    const int* i2ws = (const int*)ws + WS_I2;
    int* widx = (int*)ws + WS_WIDX;

    const int tid  = threadIdx.x;
    const int wave = tid >> 6, lane = tid & 63;
    const int half = lane >> 5;
    const int c0   = (lane & 31) << 3;
    const int rowbase = (blockIdx.x * 4 + wave) * 64;

    for (int r = 0; r < 64; ++r) {
        const int m = rowbase + r;
        int c1 = i1ws[m], c2 = i2ws[m];
        c1 = c1 < 0 ? 0 : (c1 > N_ - 1 ? N_ - 1 : c1);
        c2 = c2 < 0 ? 0 : (c2 > N_ - 1 ? N_ - 1 : c2);
        const int b = m >> 10, t = m & (T_ - 1);
        const float* zp = z + (size_t)b * C_ * T_ + t;
        const int cand = half ? c2 : c1;
        const float* ep = emb + (size_t)cand * C_;
        double sum = 0.0;
#pragma unroll
        for (int c = 0; c < 8; ++c)
            sum = fma((double)zp[(size_t)(c0 + c) * T_], (double)ep[c0 + c], sum);
#pragma unroll
        for (int off = 1; off <= 16; off <<= 1)
            sum += __shfl_xor(sum, off, 64);
        double s1 = __shfl(sum, 0, 64);
        double s2 = __shfl(sum, 32, 64);
        if (lane == 0) {
            float p1 = (float)s1, p2 = (float)s2;
            float d1 = fmaf(-2.f, p1, __fadd_rn(s_z[m], s_e[c1]));
            float d2 = fmaf(-2.f, p2, __fadd_rn(s_z[m], s_e[c2]));
            int win = ((d2 < d1) || (d2 == d1 && c2 < c1)) ? c2 : c1;
            widx[m] = win;
            out[OUT_IDX + m] = (float)win;
        }
    }
}

// ---------------- K3: gather z_q (transposed) + loss partial ----------------
__global__ __launch_bounds__(256) void vq_gather(
        const float* __restrict__ z,
        const float* __restrict__ emb,
        float* __restrict__ ws,
        float* __restrict__ out) {
    __shared__ float Ls[64][129];
    __shared__ int   idxs[64];
    __shared__ float wred[4];

    const int* widx = (const int*)ws + WS_WIDX;
    float* partial  = ws + WS_PART;

    const int tid = threadIdx.x;
    const int mg  = blockIdx.x;
    const int m0  = mg << 6;
    const int b   = m0 >> 10;
    const int t0  = m0 & (T_ - 1);

    if (tid < 64) idxs[tid] = widx[m0 + tid];
    __syncthreads();

    float lsum = 0.f;
    const int w = tid >> 6, l = tid & 63;
    const int tt2 = tid & 63, c0 = tid >> 6;
    const size_t base = (size_t)b * (C_ * T_) + t0 + tt2;
#pragma unroll
    for (int ch = 0; ch < 2; ++ch) {
        __syncthreads();
#pragma unroll
        for (int it = 0; it < 8; ++it) {
            int tt = it * 8 + w * 2 + (l >> 5);
            int cq = l & 31;
            int row = idxs[tt];
            float4 ev = *(const float4*)(emb + (size_t)row * C_ + ch * 128 + (cq << 2));
            Ls[tt][(cq << 2) + 0] = ev.x;
            Ls[tt][(cq << 2) + 1] = ev.y;
            Ls[tt][(cq << 2) + 2] = ev.z;
            Ls[tt][(cq << 2) + 3] = ev.w;
        }
        __syncthreads();
#pragma unroll
        for (int st = 0; st < 32; ++st) {
            int c_l = (st << 2) + c0;
            int c   = (ch << 7) + c_l;
            float v = Ls[tt2][c_l];
            size_t off = base + (size_t)c * T_;
            out[OUT_ZQ + off] = v;
            float d = v - z[off];
            lsum = fmaf(d, d, lsum);
        }
    }
#pragma unroll
    for (int off = 32; off >= 1; off >>= 1) lsum += __shfl_xor(lsum, off, 64);
    if (l == 0) wred[w] = lsum;
    __syncthreads();
    if (tid == 0) partial[mg] = wred[0] + wred[1] + wred[2] + wred[3];
}

// ---------------- K4: loss finisher ----------------
__global__ __launch_bounds__(256) void vq_loss(const float* __restrict__ ws,
                                               float* __restrict__ out) {
    __shared__ float wred[4];
    const int tid = threadIdx.x;
    float v = ws[WS_PART + tid];
#pragma unroll
    for (int off = 32; off >= 1; off >>= 1) v += __shfl_xor(v, off, 64);
    if ((tid & 63) == 0) wred[tid >> 6] = v;
    __syncthreads();
    if (tid == 0)
        out[OUT_LOSS] = (wred[0] + wred[1] + wred[2] + wred[3]) * (1.25f / 4194304.f);
}

extern "C" void kernel_launch(void* const* d_in, const int* in_sizes, int n_in,
                              void* d_out, int out_size, void* d_ws, size_t ws_size,
                              hipStream_t stream) {
    const float* z   = (const float*)d_in[0];
    const float* emb = (const float*)d_in[1];
    float* out = (float*)d_out;
    float* ws  = (float*)d_ws;   // ~290 KB used

    vq_sums  <<<dim3((M_ + N_) / 256), dim3(256), 0, stream>>>(z, emb, ws);
    vq_pass1 <<<dim3(M_ / TM),         dim3(256), 0, stream>>>(z, emb, ws);
    vq_pass2 <<<dim3(64),              dim3(256), 0, stream>>>(z, emb, ws, out);
    vq_gather<<<dim3(M_ / 64),         dim3(256), 0, stream>>>(z, emb, ws, out);
    vq_loss  <<<dim3(1),               dim3(256), 0, stream>>>(ws, out);
}

// Round 7
// 952.608 us; speedup vs baseline: 1.8110x; 1.8110x over previous
//
#include <hip/hip_runtime.h>

// VectorQuantizer: z [16,256,1024] fp32, emb [8192,256] fp32.
// out (FP32): [ z_q 4194304 | loss 1 | idx 16384 ]
// Ref emulation: d = fl(fl(s_z+s_e) - 2p), argmin w/ lowest-index ties.
// Fast path: p via split-bf16 (hi/lo) MFMA, 3x mfma_f32_16x16x32_bf16; per-wave
// top-3, cross-wn LDS merge (race-free), per-ns-half candidates; fp64 fixup over
// 8 candidates. Fallback (small ws): round-5 fp32 path (known-PASS).

#define C_    256
#define T_    1024
#define M_    16384
#define N_    8192

#define OUT_ZQ   0
#define OUT_LOSS 4194304
#define OUT_IDX  4194305

// ---- ws layout, fast path (float units unless noted) ----
#define WS_SZ    0           // s_z [16384]
#define WS_SE    16384       // s_e [8192]
#define WS_I1    24576       // i1 [2][16384] int
#define WS_I2    57344       // i2 [2][16384] int
#define WS_I3    90112       // i3 [2][16384] int
#define WS_PART  122880      // loss partials [256]
#define FA_OFF   524288u     // bytes: frag-linear z hi/lo, 16 MB
#define FB_OFF   17301504u   // bytes: frag-linear emb hi/lo, 8 MB
#define WS_NEED  25690112u   // bytes (proven available: R6 fast path ran)
// ---- ws layout, fallback (round-5) ----
#define O_I1     24576
#define O_I2     40960
#define O_WIDX   57344
#define O_PART   73728

typedef __attribute__((ext_vector_type(8))) short bf16x8;
typedef __attribute__((ext_vector_type(4))) float f32x4;

__device__ __forceinline__ unsigned short f2b(float f) {
    unsigned u = __float_as_uint(f);
    return (unsigned short)((u + 0x7FFFu + ((u >> 16) & 1u)) >> 16);   // RTNE
}
__device__ __forceinline__ float b2f(unsigned short u) {
    return __uint_as_float(((unsigned)u) << 16);
}

// ---------------- s_z / s_e: numpy pairwise_sum replication ----------------
__global__ __launch_bounds__(256) void vq_sums(const float* __restrict__ z,
                                               const float* __restrict__ emb,
                                               float* __restrict__ ws) {
    int gid = blockIdx.x * 256 + threadIdx.x;
    if (gid < M_) {
        int b = gid >> 10, t = gid & (T_ - 1);
        const float* zp = z + (size_t)b * C_ * T_ + t;
        float blk[2];
#pragma unroll
        for (int h = 0; h < 2; ++h) {
            float r[8];
#pragma unroll
            for (int j = 0; j < 8; ++j) {
                float v = zp[(size_t)(h * 128 + j) * T_];
                r[j] = __fmul_rn(v, v);
            }
            for (int i = 8; i < 128; i += 8)
#pragma unroll
                for (int j = 0; j < 8; ++j) {
                    float v = zp[(size_t)(h * 128 + i + j) * T_];
                    r[j] = __fadd_rn(r[j], __fmul_rn(v, v));
                }
            blk[h] = __fadd_rn(__fadd_rn(__fadd_rn(r[0], r[1]), __fadd_rn(r[2], r[3])),
                               __fadd_rn(__fadd_rn(r[4], r[5]), __fadd_rn(r[6], r[7])));
        }
        ws[WS_SZ + gid] = __fadd_rn(blk[0], blk[1]);
    } else if (gid < M_ + N_) {
        int n = gid - M_;
        const float* ep = emb + (size_t)n * C_;
        float blk[2];
#pragma unroll
        for (int h = 0; h < 2; ++h) {
            float r[8];
#pragma unroll
            for (int j = 0; j < 8; ++j) {
                float v = ep[h * 128 + j];
                r[j] = __fmul_rn(v, v);
            }
            for (int i = 8; i < 128; i += 8)
#pragma unroll
                for (int j = 0; j < 8; ++j) {
                    float v = ep[h * 128 + i + j];
                    r[j] = __fadd_rn(r[j], __fmul_rn(v, v));
                }
            blk[h] = __fadd_rn(__fadd_rn(__fadd_rn(r[0], r[1]), __fadd_rn(r[2], r[3])),
                               __fadd_rn(__fadd_rn(r[4], r[5]), __fadd_rn(r[6], r[7])));
        }
        ws[WS_SE + n] = __fadd_rn(blk[0], blk[1]);
    }
}

// ---------------- prep: z -> frag-linear bf16 hi/lo (fa) ----------------
__global__ __launch_bounds__(256) void vq_prep_a(const float* __restrict__ z,
                                                 char* __restrict__ fa) {
    int gid = blockIdx.x * 256 + threadIdx.x;     // 524288
    int m = gid & (M_ - 1), kg = gid >> 14;       // kg in [0,32)
    const float* zp = z + (size_t)(m >> 10) * C_ * T_ + (m & (T_ - 1));
    unsigned hi[8], lo[8];
#pragma unroll
    for (int j = 0; j < 8; ++j) {
        float v = zp[(size_t)(kg * 8 + j) * T_];
        unsigned short h = f2b(v);
        hi[j] = h;
        lo[j] = f2b(v - b2f(h));
    }
    int mt = m >> 4, kt = kg >> 2, lane = (kg & 3) * 16 + (m & 15);
    size_t base = ((size_t)((mt * 8 + kt) * 2) << 10) + (lane << 4);
    uint4 hv = {hi[0] | (hi[1] << 16), hi[2] | (hi[3] << 16), hi[4] | (hi[5] << 16), hi[6] | (hi[7] << 16)};
    uint4 lv = {lo[0] | (lo[1] << 16), lo[2] | (lo[3] << 16), lo[4] | (lo[5] << 16), lo[6] | (lo[7] << 16)};
    *(uint4*)(fa + base) = hv;
    *(uint4*)(fa + base + 1024) = lv;
}

// ---------------- prep: emb -> frag-linear bf16 hi/lo (fb) ----------------
__global__ __launch_bounds__(256) void vq_prep_b(const float* __restrict__ emb,
                                                 char* __restrict__ fb) {
    int gid = blockIdx.x * 256 + threadIdx.x;     // 262144
    int n = gid >> 5, kg = gid & 31;
    const float* ep = emb + (size_t)n * C_ + kg * 8;
    unsigned hi[8], lo[8];
#pragma unroll
    for (int j = 0; j < 8; ++j) {
        float v = ep[j];
        unsigned short h = f2b(v);
        hi[j] = h;
        lo[j] = f2b(v - b2f(h));
    }
    int nt = n >> 4, kt = kg >> 2, lane = (kg & 3) * 16 + (n & 15);
    size_t base = ((size_t)((nt * 8 + kt) * 2) << 10) + (lane << 4);
    uint4 hv = {hi[0] | (hi[1] << 16), hi[2] | (hi[3] << 16), hi[4] | (hi[5] << 16), hi[6] | (hi[7] << 16)};
    uint4 lv = {lo[0] | (lo[1] << 16), lo[2] | (lo[3] << 16), lo[4] | (lo[5] << 16), lo[6] | (lo[7] << 16)};
    *(uint4*)(fb + base) = hv;
    *(uint4*)(fb + base + 1024) = lv;
}

// ---------------- pass1: MFMA split-bf16 GEMM + per-ns-half top-3 ----------------
// grid (128, 2), block 256 (4 waves, 2x2). Block: 128m x 128n per nt, K=256.
__global__ __launch_bounds__(256, 1) void vq_mfma(
        const char* __restrict__ fa, const char* __restrict__ fb,
        const float* __restrict__ sz, const float* __restrict__ se,
        int* __restrict__ i1ws, int* __restrict__ i2ws, int* __restrict__ i3ws) {
    __shared__ __align__(16) char ldsA[16384];
    __shared__ __align__(16) char ldsB[16384];
    const int tid = threadIdx.x;
    const int lane = tid & 63;
    const int w = tid >> 6, wm = w & 1, wn = w >> 1;
    const int mt0 = blockIdx.x;
    const int ns  = blockIdx.y;
    const int quad = lane >> 4, li = lane & 15;

    float szr[16];
#pragma unroll
    for (int ms = 0; ms < 4; ++ms)
#pragma unroll
        for (int r = 0; r < 4; ++r)
            szr[ms * 4 + r] = sz[mt0 * 128 + (wm * 4 + ms) * 16 + quad * 4 + r];

    float v1[16], v2[16], v3[16];
    int   x1[16], x2[16], x3[16];
#pragma unroll
    for (int s = 0; s < 16; ++s) {
        v1[s] = INFINITY; v2[s] = INFINITY; v3[s] = INFINITY;
        x1[s] = 0x7FFFFFFF; x2[s] = 0x7FFFFFFF; x3[s] = 0x7FFFFFFF;
    }

    const int f = tid >> 4, pos = (tid & 15) << 4;

    for (int nt = 0; nt < 32; ++nt) {
        f32x4 acc[4][4];
#pragma unroll
        for (int i = 0; i < 4; ++i)
#pragma unroll
            for (int j = 0; j < 4; ++j) acc[i][j] = (f32x4){0.f, 0.f, 0.f, 0.f};
        const int ntile0 = ns * 256 + nt * 8;

        for (int kt = 0; kt < 8; ++kt) {
            __syncthreads();
            {
                const char* srcA = fa + ((((size_t)(mt0 * 8 + (f >> 1)) * 8 + kt) * 2 + (f & 1)) << 10) + pos;
                const char* srcB = fb + ((((size_t)(ntile0 + (f >> 1)) * 8 + kt) * 2 + (f & 1)) << 10) + pos;
                char* dA = ldsA + (f << 10) + pos;
                char* dB = ldsB + (f << 10) + pos;
#pragma unroll
                for (int i = 0; i < 4; ++i) {
                    *(uint4*)(dA + i * 256) = *(const uint4*)(srcA + i * 256);
                    *(uint4*)(dB + i * 256) = *(const uint4*)(srcB + i * 256);
                }
            }
            __syncthreads();
            bf16x8 a[4][2];
#pragma unroll
            for (int ms = 0; ms < 4; ++ms) {
                a[ms][0] = *(const bf16x8*)(ldsA + (((wm * 4 + ms) * 2 + 0) << 10) + (lane << 4));
                a[ms][1] = *(const bf16x8*)(ldsA + (((wm * 4 + ms) * 2 + 1) << 10) + (lane << 4));
            }
#pragma unroll
            for (int nsb = 0; nsb < 4; ++nsb) {
                bf16x8 bh = *(const bf16x8*)(ldsB + (((wn * 4 + nsb) * 2 + 0) << 10) + (lane << 4));
                bf16x8 bl = *(const bf16x8*)(ldsB + (((wn * 4 + nsb) * 2 + 1) << 10) + (lane << 4));
#pragma unroll
                for (int ms = 0; ms < 4; ++ms) {
                    f32x4 c = acc[ms][nsb];
                    c = __builtin_amdgcn_mfma_f32_16x16x32_bf16(a[ms][0], bh, c, 0, 0, 0);
                    c = __builtin_amdgcn_mfma_f32_16x16x32_bf16(a[ms][0], bl, c, 0, 0, 0);
                    c = __builtin_amdgcn_mfma_f32_16x16x32_bf16(a[ms][1], bh, c, 0, 0, 0);
                    acc[ms][nsb] = c;
                }
            }
        }
        // epilogue: ref-formula quantized score + running top-3 (ascending n/thread)
#pragma unroll
        for (int nsb = 0; nsb < 4; ++nsb) {
            const int ncol = ns * 4096 + nt * 128 + (wn * 4 + nsb) * 16 + li;
            const float sev = se[ncol];
#pragma unroll
            for (int ms = 0; ms < 4; ++ms) {
                f32x4 c = acc[ms][nsb];
#pragma unroll
                for (int r = 0; r < 4; ++r) {
                    float s = fmaf(-2.f, c[r], __fadd_rn(szr[ms * 4 + r], sev));
                    const int sl = ms * 4 + r;
                    if (s < v1[sl]) {
                        v3[sl] = v2[sl]; x3[sl] = x2[sl];
                        v2[sl] = v1[sl]; x2[sl] = x1[sl];
                        v1[sl] = s; x1[sl] = ncol;
                    } else if (s < v2[sl]) {
                        v3[sl] = v2[sl]; x3[sl] = x2[sl];
                        v2[sl] = s; x2[sl] = ncol;
                    } else if (s < v3[sl]) {
                        v3[sl] = s; x3[sl] = ncol;
                    }
                }
            }
        }
    }

    // cross-li butterfly merge of sorted triples, then cross-wn merge via LDS
    __syncthreads();                       // done reading ldsA/ldsB
    float* sv = (float*)ldsA;              // scratch: v1/v2/v3 at 0/256/512,
    int*   sx = (int*)ldsA;                //          x1/x2/x3 at 768/1024/1280
#pragma unroll
    for (int sl = 0; sl < 16; ++sl) {
        float a1 = v1[sl], a2 = v2[sl], a3 = v3[sl];
        int   y1 = x1[sl], y2 = x2[sl], y3 = x3[sl];
#pragma unroll
        for (int off = 8; off >= 1; off >>= 1) {
            float o1 = __shfl_xor(a1, off, 64), o2 = __shfl_xor(a2, off, 64), o3 = __shfl_xor(a3, off, 64);
            int   p1 = __shfl_xor(y1, off, 64), p2 = __shfl_xor(y2, off, 64), p3 = __shfl_xor(y3, off, 64);
#pragma unroll
            for (int t = 0; t < 3; ++t) {
                float ov = t == 0 ? o1 : (t == 1 ? o2 : o3);
                int   op = t == 0 ? p1 : (t == 1 ? p2 : p3);
                bool b1 = (ov < a1) || (ov == a1 && op < y1);
                bool b2 = (ov < a2) || (ov == a2 && op < y2);
                bool b3 = (ov < a3) || (ov == a3 && op < y3);
                if (b1)      { a3 = a2; y3 = y2; a2 = a1; y2 = y1; a1 = ov; y1 = op; }
                else if (b2) { a3 = a2; y3 = y2; a2 = ov; y2 = op; }
                else if (b3) { a3 = ov; y3 = op; }
            }
        }
        if (li == 0) {
            int row_local = (wm * 4 + (sl >> 2)) * 16 + quad * 4 + (sl & 3);
            int o = wn * 128 + row_local;
            sv[o] = a1; sv[256 + o] = a2; sv[512 + o] = a3;
            sx[768 + o] = y1; sx[1024 + o] = y2; sx[1280 + o] = y3;
        }
    }
    __syncthreads();
    if (tid < 128) {
        float m1 = INFINITY, m2 = INFINITY, m3 = INFINITY;
        int   y1 = 0x7FFFFFFF, y2 = 0x7FFFFFFF, y3 = 0x7FFFFFFF;
#pragma unroll
        for (int h = 0; h < 2; ++h) {
            int o = h * 128 + tid;
#pragma unroll
            for (int t = 0; t < 3; ++t) {
                float ov = sv[t * 256 + o];
                int   op = sx[768 + t * 256 + o];
                bool b1 = (ov < m1) || (ov == m1 && op < y1);
                bool b2 = (ov < m2) || (ov == m2 && op < y2);
                bool b3 = (ov < m3) || (ov == m3 && op < y3);
                if (b1)      { m3 = m2; y3 = y2; m2 = m1; y2 = y1; m1 = ov; y1 = op; }
                else if (b2) { m3 = m2; y3 = y2; m2 = ov; y2 = op; }
                else if (b3) { m3 = ov; y3 = op; }
            }
        }
        int row = mt0 * 128 + tid;
        i1ws[ns * M_ + row] = y1;
        i2ws[ns * M_ + row] = y2;
        i3ws[ns * M_ + row] = y3;
    }
}

// ---------------- pass2: fp64 fixup over 8 candidates + idx out ----------------
// grid 256, block 256; wave owns 16 rows. oct (8 lanes) per candidate.
__global__ __launch_bounds__(256) void vq_pick(
        const float* __restrict__ z, const float* __restrict__ emb,
        const float* __restrict__ ws, const int* __restrict__ i1ws,
        const int* __restrict__ i2ws, const int* __restrict__ i3ws,
        float* __restrict__ out) {
    const float* sz = ws + WS_SZ;
    const float* se = ws + WS_SE;
    const int tid = threadIdx.x;
    const int wave = tid >> 6, lane = tid & 63, oct = lane >> 3, u = lane & 7;
    const int rowbase = (blockIdx.x * 4 + wave) * 16;

    for (int r = 0; r < 16; ++r) {
        const int m = rowbase + r;
        int q0 = i1ws[m], q1 = i2ws[m], q2 = i3ws[m];
        int q3 = i1ws[M_ + m], q4 = i2ws[M_ + m], q5 = i3ws[M_ + m];
        q0 = q0 < 0 ? 0 : (q0 > N_ - 1 ? N_ - 1 : q0);
        q1 = q1 < 0 ? 0 : (q1 > N_ - 1 ? N_ - 1 : q1);
        q2 = q2 < 0 ? 0 : (q2 > N_ - 1 ? N_ - 1 : q2);
        q3 = q3 < 0 ? 0 : (q3 > N_ - 1 ? N_ - 1 : q3);
        q4 = q4 < 0 ? 0 : (q4 > N_ - 1 ? N_ - 1 : q4);
        q5 = q5 < 0 ? 0 : (q5 > N_ - 1 ? N_ - 1 : q5);
        int cand = oct == 0 ? q0 : oct == 1 ? q1 : oct == 2 ? q2 : oct == 3 ? q3
                 : oct == 4 ? q4 : oct == 5 ? q5 : oct == 6 ? q0 : q3;
        const float* zp = z + (size_t)(m >> 10) * C_ * T_ + (m & (T_ - 1));
        const float* ep = emb + (size_t)cand * C_;
        double sum = 0.0;
#pragma unroll
        for (int cc = 0; cc < 32; ++cc)
            sum = fma((double)zp[(size_t)(u * 32 + cc) * T_], (double)ep[u * 32 + cc], sum);
        sum += __shfl_xor(sum, 1, 64);
        sum += __shfl_xor(sum, 2, 64);
        sum += __shfl_xor(sum, 4, 64);
        double s0 = __shfl(sum, 0, 64),  s1 = __shfl(sum, 8, 64);
        double s2 = __shfl(sum, 16, 64), s3 = __shfl(sum, 24, 64);
        double s4 = __shfl(sum, 32, 64), s5 = __shfl(sum, 40, 64);
        if (lane == 0) {
            float szm = sz[m];
            float d0 = fmaf(-2.f, (float)s0, __fadd_rn(szm, se[q0]));
            float d1 = fmaf(-2.f, (float)s1, __fadd_rn(szm, se[q1]));
            float d2 = fmaf(-2.f, (float)s2, __fadd_rn(szm, se[q2]));
            float d3 = fmaf(-2.f, (float)s3, __fadd_rn(szm, se[q3]));
            float d4 = fmaf(-2.f, (float)s4, __fadd_rn(szm, se[q4]));
            float d5 = fmaf(-2.f, (float)s5, __fadd_rn(szm, se[q5]));
            float bd = d0; int bi = q0;
            if (d1 < bd || (d1 == bd && q1 < bi)) { bd = d1; bi = q1; }
            if (d2 < bd || (d2 == bd && q2 < bi)) { bd = d2; bi = q2; }
            if (d3 < bd || (d3 == bd && q3 < bi)) { bd = d3; bi = q3; }
            if (d4 < bd || (d4 == bd && q4 < bi)) { bd = d4; bi = q4; }
            if (d5 < bd || (d5 == bd && q5 < bi)) { bd = d5; bi = q5; }
            out[OUT_IDX + m] = (float)bi;
        }
    }
}

// ---------------- fallback round-5 pass1 (fp32 VALU GEMM, top-2 global) ----------------
__global__ __launch_bounds__(256) void vq_pass1_fp32(
        const float* __restrict__ z,
        const float* __restrict__ emb,
        float* __restrict__ ws) {
    __shared__ float As[32][68];
    __shared__ float Bs[32][68];
    const float* s_z = ws + WS_SZ;
    const float* s_e = ws + WS_SE;
    int* i1ws = (int*)ws + O_I1;
    int* i2ws = (int*)ws + O_I2;
    const int tid = threadIdx.x;
    const int mt  = blockIdx.x;
    const int tx  = tid & 15, ty = tid >> 4;
    const int b   = mt >> 4;
    const int t0  = (mt << 6) & (T_ - 1);
    const float* zbase = z + (size_t)b * C_ * T_ + t0;
    const int a_k = tid >> 4;
    const int a_m = (tid & 15) << 2;
    const int b_j = tid >> 2;
    const int b_q = (tid & 3) << 3;
    const float4 sz4 = *(const float4*)(s_z + mt * 64 + (ty << 2));
    const float szv[4] = {sz4.x, sz4.y, sz4.z, sz4.w};
    float v1[4], v2[4];
    int   i1[4], i2[4];
#pragma unroll
    for (int i = 0; i < 4; ++i) {
        v1[i] = INFINITY; v2[i] = INFINITY;
        i1[i] = 0x7FFFFFFF; i2[i] = 0x7FFFFFFF;
    }
    for (int nt = 0; nt < N_ / 64; ++nt) {
        const int n0 = nt * 64;
        float acc[4][4];
#pragma unroll
        for (int i = 0; i < 4; ++i)
#pragma unroll
            for (int j = 0; j < 4; ++j) acc[i][j] = 0.f;
        for (int kt = 0; kt < C_; kt += 32) {
            __syncthreads();
#pragma unroll
            for (int p = 0; p < 2; ++p) {
                int k = a_k + p * 16;
                float4 af = *(const float4*)(zbase + (size_t)(kt + k) * T_ + a_m);
                *(float4*)&As[k][a_m] = af;
            }
            {
                const float* ep = emb + (size_t)(n0 + b_j) * C_ + kt + b_q;
                float4 e0 = ((const float4*)ep)[0];
                float4 e1 = ((const float4*)ep)[1];
                Bs[b_q + 0][b_j] = e0.x; Bs[b_q + 1][b_j] = e0.y;
                Bs[b_q + 2][b_j] = e0.z; Bs[b_q + 3][b_j] = e0.w;
                Bs[b_q + 4][b_j] = e1.x; Bs[b_q + 5][b_j] = e1.y;
                Bs[b_q + 6][b_j] = e1.z; Bs[b_q + 7][b_j] = e1.w;
            }
            __syncthreads();
#pragma unroll
            for (int k = 0; k < 32; ++k) {
                const float4 a  = *(const float4*)&As[k][ty << 2];
                const float4 bv = *(const float4*)&Bs[k][tx << 2];
                acc[0][0] = fmaf(a.x, bv.x, acc[0][0]);
                acc[0][1] = fmaf(a.x, bv.y, acc[0][1]);
                acc[0][2] = fmaf(a.x, bv.z, acc[0][2]);
                acc[0][3] = fmaf(a.x, bv.w, acc[0][3]);
                acc[1][0] = fmaf(a.y, bv.x, acc[1][0]);
                acc[1][1] = fmaf(a.y, bv.y, acc[1][1]);
                acc[1][2] = fmaf(a.y, bv.z, acc[1][2]);
                acc[1][3] = fmaf(a.y, bv.w, acc[1][3]);
                acc[2][0] = fmaf(a.z, bv.x, acc[2][0]);
                acc[2][1] = fmaf(a.z, bv.y, acc[2][1]);
                acc[2][2] = fmaf(a.z, bv.z, acc[2][2]);
                acc[2][3] = fmaf(a.z, bv.w, acc[2][3]);
                acc[3][0] = fmaf(a.w, bv.x, acc[3][0]);
                acc[3][1] = fmaf(a.w, bv.y, acc[3][1]);
                acc[3][2] = fmaf(a.w, bv.z, acc[3][2]);
                acc[3][3] = fmaf(a.w, bv.w, acc[3][3]);
            }
        }
        const float4 se4 = *(const float4*)(s_e + n0 + (tx << 2));
        const float sev[4] = {se4.x, se4.y, se4.z, se4.w};
#pragma unroll
        for (int j = 0; j < 4; ++j) {
            const int n = n0 + (tx << 2) + j;
#pragma unroll
            for (int i = 0; i < 4; ++i) {
                float A = __fadd_rn(szv[i], sev[j]);
                float s = fmaf(-2.f, acc[i][j], A);
                if (s < v1[i]) { v2[i] = v1[i]; i2[i] = i1[i]; v1[i] = s; i1[i] = n; }
                else if (s < v2[i]) { v2[i] = s; i2[i] = n; }
            }
        }
    }
#pragma unroll
    for (int i = 0; i < 4; ++i) {
        float a1 = v1[i], a2 = v2[i];
        int   y1 = i1[i], y2 = i2[i];
#pragma unroll
        for (int off = 8; off >= 1; off >>= 1) {
            float o1 = __shfl_xor(a1, off, 64); int p1 = __shfl_xor(y1, off, 64);
            float o2 = __shfl_xor(a2, off, 64); int p2 = __shfl_xor(y2, off, 64);
            bool alt = (o1 < a1) || (o1 == a1 && p1 < y1);
            float w1 = alt ? o1 : a1; int q1 = alt ? p1 : y1;
            float lv = alt ? a1 : o1; int lq = alt ? y1 : p1;
            float wv = alt ? o2 : a2; int wq = alt ? p2 : y2;
            bool sb = (lv < wv) || (lv == wv && lq < wq);
            a2 = sb ? lv : wv; y2 = sb ? lq : wq;
            a1 = w1; y1 = q1;
        }
        if (tx == 0) {
            int m = mt * 64 + (ty << 2) + i;
            i1ws[m] = y1;
            i2ws[m] = y2;
        }
    }
}

__global__ __launch_bounds__(256) void vq_pass2_fp32(
        const float* __restrict__ z,
        const float* __restrict__ emb,
        float* __restrict__ ws,
        float* __restrict__ out) {
    const float* s_z = ws + WS_SZ;
    const float* s_e = ws + WS_SE;
    const int* i1ws = (const int*)ws + O_I1;
    const int* i2ws = (const int*)ws + O_I2;
    const int tid  = threadIdx.x;
    const int wave = tid >> 6, lane = tid & 63;
    const int half = lane >> 5;
    const int c0   = (lane & 31) << 3;
    const int rowbase = (blockIdx.x * 4 + wave) * 64;
    for (int r = 0; r < 64; ++r) {
        const int m = rowbase + r;
        int c1 = i1ws[m], c2 = i2ws[m];
        c1 = c1 < 0 ? 0 : (c1 > N_ - 1 ? N_ - 1 : c1);
        c2 = c2 < 0 ? 0 : (c2 > N_ - 1 ? N_ - 1 : c2);
        const int b = m >> 10, t = m & (T_ - 1);
        const float* zp = z + (size_t)b * C_ * T_ + t;
        const int cand = half ? c2 : c1;
        const float* ep = emb + (size_t)cand * C_;
        double sum = 0.0;
#pragma unroll
        for (int c = 0; c < 8; ++c)
            sum = fma((double)zp[(size_t)(c0 + c) * T_], (double)ep[c0 + c], sum);
#pragma unroll
        for (int off = 1; off <= 16; off <<= 1)
            sum += __shfl_xor(sum, off, 64);
        double s1 = __shfl(sum, 0, 64);
        double s2 = __shfl(sum, 32, 64);
        if (lane == 0) {
            float p1 = (float)s1, p2 = (float)s2;
            float d1 = fmaf(-2.f, p1, __fadd_rn(s_z[m], s_e[c1]));
            float d2 = fmaf(-2.f, p2, __fadd_rn(s_z[m], s_e[c2]));
            int win = ((d2 < d1) || (d2 == d1 && c2 < c1)) ? c2 : c1;
            out[OUT_IDX + m] = (float)win;
        }
    }
}

// ---------------- gather z_q (transposed) + loss partial; idx from out ----------------
__global__ __launch_bounds__(256) void vq_gather(
        const float* __restrict__ z,
        const float* __restrict__ emb,
        float* __restrict__ partial,
        float* __restrict__ out) {
    __shared__ float Ls[64][129];
    __shared__ int   idxs[64];
    __shared__ float wred[4];
    const int tid = threadIdx.x;
    const int mg  = blockIdx.x;
    const int m0  = mg << 6;
    const int b   = m0 >> 10;
    const int t0  = m0 & (T_ - 1);
    if (tid < 64) {
        int ix = (int)out[OUT_IDX + m0 + tid];
        idxs[tid] = ix < 0 ? 0 : (ix > N_ - 1 ? N_ - 1 : ix);
    }
    __syncthreads();
    float lsum = 0.f;
    const int w = tid >> 6, l = tid & 63;
    const int tt2 = tid & 63, c0 = tid >> 6;
    const size_t base = (size_t)b * (C_ * T_) + t0 + tt2;
#pragma unroll
    for (int ch = 0; ch < 2; ++ch) {
        __syncthreads();
#pragma unroll
        for (int it = 0; it < 8; ++it) {
            int tt = it * 8 + w * 2 + (l >> 5);
            int cq = l & 31;
            int row = idxs[tt];
            float4 ev = *(const float4*)(emb + (size_t)row * C_ + ch * 128 + (cq << 2));
            Ls[tt][(cq << 2) + 0] = ev.x;
            Ls[tt][(cq << 2) + 1] = ev.y;
            Ls[tt][(cq << 2) + 2] = ev.z;
            Ls[tt][(cq << 2) + 3] = ev.w;
        }
        __syncthreads();
#pragma unroll
        for (int st = 0; st < 32; ++st) {
            int c_l = (st << 2) + c0;
            int c   = (ch << 7) + c_l;
            float v = Ls[tt2][c_l];
            size_t off = base + (size_t)c * T_;
            out[OUT_ZQ + off] = v;
            float d = v - z[off];
            lsum = fmaf(d, d, lsum);
        }
    }
#pragma unroll
    for (int off = 32; off >= 1; off >>= 1) lsum += __shfl_xor(lsum, off, 64);
    if (l == 0) wred[w] = lsum;
    __syncthreads();
    if (tid == 0) partial[mg] = wred[0] + wred[1] + wred[2] + wred[3];
}

__global__ __launch_bounds__(256) void vq_loss(const float* __restrict__ partial,
                                               float* __restrict__ out) {
    __shared__ float wred[4];
    const int tid = threadIdx.x;
    float v = partial[tid];
#pragma unroll
    for (int off = 32; off >= 1; off >>= 1) v += __shfl_xor(v, off, 64);
    if ((tid & 63) == 0) wred[tid >> 6] = v;
    __syncthreads();
    if (tid == 0)
        out[OUT_LOSS] = (wred[0] + wred[1] + wred[2] + wred[3]) * (1.25f / 4194304.f);
}

extern "C" void kernel_launch(void* const* d_in, const int* in_sizes, int n_in,
                              void* d_out, int out_size, void* d_ws, size_t ws_size,
                              hipStream_t stream) {
    const float* z   = (const float*)d_in[0];
    const float* emb = (const float*)d_in[1];
    float* out = (float*)d_out;
    float* ws  = (float*)d_ws;

    vq_sums<<<dim3((M_ + N_) / 256), dim3(256), 0, stream>>>(z, emb, ws);

    if (ws_size >= WS_NEED) {   // fast MFMA path
        char* fa = (char*)d_ws + FA_OFF;
        char* fb = (char*)d_ws + FB_OFF;
        int* i1 = (int*)ws + WS_I1;
        int* i2 = (int*)ws + WS_I2;
        int* i3 = (int*)ws + WS_I3;
        vq_prep_a<<<dim3(2048), dim3(256), 0, stream>>>(z, fa);
        vq_prep_b<<<dim3(1024), dim3(256), 0, stream>>>(emb, fb);
        vq_mfma<<<dim3(128, 2), dim3(256), 0, stream>>>(fa, fb, ws + WS_SZ, ws + WS_SE, i1, i2, i3);
        vq_pick<<<dim3(256), dim3(256), 0, stream>>>(z, emb, ws, i1, i2, i3, out);
        vq_gather<<<dim3(M_ / 64), dim3(256), 0, stream>>>(z, emb, ws + WS_PART, out);
        vq_loss<<<dim3(1), dim3(256), 0, stream>>>(ws + WS_PART, out);
    } else {                    // round-5 fallback (known-PASS)
        vq_pass1_fp32<<<dim3(M_ / 64), dim3(256), 0, stream>>>(z, emb, ws);
        vq_pass2_fp32<<<dim3(64), dim3(256), 0, stream>>>(z, emb, ws, out);
        vq_gather<<<dim3(M_ / 64), dim3(256), 0, stream>>>(z, emb, ws + O_PART, out);
        vq_loss<<<dim3(1), dim3(256), 0, stream>>>(ws + O_PART, out);
    }
}

// Round 8
// 369.808 us; speedup vs baseline: 4.6651x; 2.5760x over previous
//
#include <hip/hip_runtime.h>

// VectorQuantizer: z [16,256,1024] fp32, emb [8192,256] fp32.
// out (FP32): [ z_q 4194304 | loss 1 | idx 16384 ]
// Ref emulation: d = fl(fl(s_z+s_e) - 2p), argmin w/ lowest-index ties.
// Fast path: split-bf16 (hi/lo) MFMA GEMM; A resident in LDS (staged once from z),
// B from prep'd frag-linear ws; packed-u64 per-128-col chunk minima -> ws;
// top-4-of-64 fp64 fixup (arithmetic identical to R5/R7's validated pass2).

#define C_    256
#define T_    1024
#define M_    16384
#define N_    8192

#define OUT_ZQ   0
#define OUT_LOSS 4194304
#define OUT_IDX  4194305

// ---- ws layout, fast path ----
#define WS_SZ    0           // s_z [16384] float
#define WS_SE    16384       // s_e [8192] float
#define WS_PART  24576       // loss partials [256] float   (ends byte 99328)
#define MIN_OFF  131072u     // bytes: u64 minima [16384 rows][64 cells] = 8 MB
#define FB_OFF   8519680u    // bytes: frag-linear emb hi/lo, 8 MB
#define WS_NEED  16908288u   // bytes (< 25.69 MB proven available)
// ---- ws layout, fallback (round-5, known-PASS) ----
#define O_I1     24576
#define O_I2     40960
#define O_PART   73728

typedef __attribute__((ext_vector_type(8))) short bf16x8;
typedef __attribute__((ext_vector_type(4))) float f32x4;
typedef unsigned long long ull;

__device__ __forceinline__ unsigned short f2b(float f) {
    unsigned u = __float_as_uint(f);
    return (unsigned short)((u + 0x7FFFu + ((u >> 16) & 1u)) >> 16);   // RTNE
}
__device__ __forceinline__ float b2f(unsigned short u) {
    return __uint_as_float(((unsigned)u) << 16);
}

// ---------------- s_z / s_e: numpy pairwise_sum replication ----------------
__global__ __launch_bounds__(256) void vq_sums(const float* __restrict__ z,
                                               const float* __restrict__ emb,
                                               float* __restrict__ ws) {
    int gid = blockIdx.x * 256 + threadIdx.x;
    if (gid < M_) {
        int b = gid >> 10, t = gid & (T_ - 1);
        const float* zp = z + (size_t)b * C_ * T_ + t;
        float blk[2];
#pragma unroll
        for (int h = 0; h < 2; ++h) {
            float r[8];
#pragma unroll
            for (int j = 0; j < 8; ++j) {
                float v = zp[(size_t)(h * 128 + j) * T_];
                r[j] = __fmul_rn(v, v);
            }
            for (int i = 8; i < 128; i += 8)
#pragma unroll
                for (int j = 0; j < 8; ++j) {
                    float v = zp[(size_t)(h * 128 + i + j) * T_];
                    r[j] = __fadd_rn(r[j], __fmul_rn(v, v));
                }
            blk[h] = __fadd_rn(__fadd_rn(__fadd_rn(r[0], r[1]), __fadd_rn(r[2], r[3])),
                               __fadd_rn(__fadd_rn(r[4], r[5]), __fadd_rn(r[6], r[7])));
        }
        ws[WS_SZ + gid] = __fadd_rn(blk[0], blk[1]);
    } else if (gid < M_ + N_) {
        int n = gid - M_;
        const float* ep = emb + (size_t)n * C_;
        float blk[2];
#pragma unroll
        for (int h = 0; h < 2; ++h) {
            float r[8];
#pragma unroll
            for (int j = 0; j < 8; ++j) {
                float v = ep[h * 128 + j];
                r[j] = __fmul_rn(v, v);
            }
            for (int i = 8; i < 128; i += 8)
#pragma unroll
                for (int j = 0; j < 8; ++j) {
                    float v = ep[h * 128 + i + j];
                    r[j] = __fadd_rn(r[j], __fmul_rn(v, v));
                }
            blk[h] = __fadd_rn(__fadd_rn(__fadd_rn(r[0], r[1]), __fadd_rn(r[2], r[3])),
                               __fadd_rn(__fadd_rn(r[4], r[5]), __fadd_rn(r[6], r[7])));
        }
        ws[WS_SE + n] = __fadd_rn(blk[0], blk[1]);
    }
}

// ---------------- prep: emb -> frag-linear bf16 hi/lo (fb) ----------------
__global__ __launch_bounds__(256) void vq_prep_b(const float* __restrict__ emb,
                                                 char* __restrict__ fb) {
    int gid = blockIdx.x * 256 + threadIdx.x;     // 262144
    int n = gid >> 5, kg = gid & 31;
    const float* ep = emb + (size_t)n * C_ + kg * 8;
    unsigned hi[8], lo[8];
#pragma unroll
    for (int j = 0; j < 8; ++j) {
        float v = ep[j];
        unsigned short h = f2b(v);
        hi[j] = h;
        lo[j] = f2b(v - b2f(h));
    }
    int nt = n >> 4, kt = kg >> 2, lane = (kg & 3) * 16 + (n & 15);
    size_t base = ((size_t)((nt * 8 + kt) * 2) << 10) + (lane << 4);
    uint4 hv = {hi[0] | (hi[1] << 16), hi[2] | (hi[3] << 16), hi[4] | (hi[5] << 16), hi[6] | (hi[7] << 16)};
    uint4 lv = {lo[0] | (lo[1] << 16), lo[2] | (lo[3] << 16), lo[4] | (lo[5] << 16), lo[6] | (lo[7] << 16)};
    *(uint4*)(fb + base) = hv;
    *(uint4*)(fb + base + 1024) = lv;
}

// ---------------- pass1: MFMA GEMM, A resident, chunk-min epilogue ----------------
// grid (256 m-blocks, 2 ns), block 256 (4 waves 2x2: wave = 32m x 64n).
__global__ __launch_bounds__(256, 2) void vq_mfma2(
        const float* __restrict__ z, const char* __restrict__ fb,
        const float* __restrict__ sz, const float* __restrict__ se,
        ull* __restrict__ minima) {
    __shared__ __align__(16) char ldsA[65536];   // 64m x 256k hi/lo, frag-linear
    __shared__ __align__(16) char ldsB[16384];   // 128n x 32k hi/lo, frag-linear

    const int tid = threadIdx.x;
    const int lane = tid & 63;
    const int w = tid >> 6, wm = w & 1, wn = w >> 1;
    const int quad = lane >> 4, li = lane & 15;
    const int mb = blockIdx.x, ns = blockIdx.y;

    // ---- one-time A staging: z[b][c][t0..t0+64) -> hi/lo frag-linear LDS ----
    {
        const float* zb = z + (size_t)(mb >> 4) * C_ * T_ + ((mb & 15) << 6);
#pragma unroll
        for (int p = 0; p < 4; ++p) {
            int c  = p * 64 + (tid >> 2);
            int tq = tid & 3;
            const float* src = zb + (size_t)c * T_ + tq * 16;
            int kt = c >> 5, kg3 = (c >> 3) & 3, j = c & 7;
            unsigned short* d0 = (unsigned short*)(ldsA + (((tq * 8 + kt) * 2 + 0) << 10) + (kg3 << 8) + (j << 1));
            unsigned short* d1 = (unsigned short*)(ldsA + (((tq * 8 + kt) * 2 + 1) << 10) + (kg3 << 8) + (j << 1));
#pragma unroll
            for (int u = 0; u < 4; ++u) {
                float4 v = *(const float4*)(src + u * 4);
                float vv[4] = {v.x, v.y, v.z, v.w};
#pragma unroll
                for (int e = 0; e < 4; ++e) {
                    unsigned short h = f2b(vv[e]);
                    unsigned short l = f2b(vv[e] - b2f(h));
                    int i = u * 4 + e;
                    d0[i * 8] = h;            // i*16 bytes
                    d1[i * 8] = l;
                }
            }
        }
    }

    float szr[8];
#pragma unroll
    for (int mt = 0; mt < 2; ++mt)
#pragma unroll
        for (int r = 0; r < 4; ++r)
            szr[mt * 4 + r] = sz[(mb << 6) + (wm << 5) + (mt << 4) + (quad << 2) + r];

    ull key[8];
#pragma unroll
    for (int s = 0; s < 8; ++s) key[s] = ~0ULL;

    const int f = tid >> 4, pos = (tid & 15) << 4;

    for (int nt = 0; nt < 32; ++nt) {
        f32x4 acc[2][4];
#pragma unroll
        for (int i = 0; i < 2; ++i)
#pragma unroll
            for (int j = 0; j < 4; ++j) acc[i][j] = (f32x4){0.f, 0.f, 0.f, 0.f};
        const int ntile0 = ns * 256 + nt * 8;

        for (int kt = 0; kt < 8; ++kt) {
            __syncthreads();                  // prior reads of ldsB done (and A visible, iter 0)
            {
                const char* srcB = fb + ((((size_t)(ntile0 + (f >> 1)) * 8 + kt) * 2 + (f & 1)) << 10) + pos;
                char* dB = ldsB + (f << 10) + pos;
#pragma unroll
                for (int i = 0; i < 4; ++i)
                    *(uint4*)(dB + i * 256) = *(const uint4*)(srcB + i * 256);
            }
            __syncthreads();
            bf16x8 a[2][2];
#pragma unroll
            for (int mt = 0; mt < 2; ++mt) {
                a[mt][0] = *(const bf16x8*)(ldsA + ((((wm * 2 + mt) * 8 + kt) * 2 + 0) << 10) + (lane << 4));
                a[mt][1] = *(const bf16x8*)(ldsA + ((((wm * 2 + mt) * 8 + kt) * 2 + 1) << 10) + (lane << 4));
            }
#pragma unroll
            for (int nt4 = 0; nt4 < 4; ++nt4) {
                bf16x8 bh = *(const bf16x8*)(ldsB + ((((wn * 4 + nt4) * 2 + 0)) << 10) + (lane << 4));
                bf16x8 bl = *(const bf16x8*)(ldsB + ((((wn * 4 + nt4) * 2 + 1)) << 10) + (lane << 4));
#pragma unroll
                for (int mt = 0; mt < 2; ++mt) {
                    f32x4 c = acc[mt][nt4];
                    c = __builtin_amdgcn_mfma_f32_16x16x32_bf16(a[mt][0], bh, c, 0, 0, 0);
                    c = __builtin_amdgcn_mfma_f32_16x16x32_bf16(a[mt][0], bl, c, 0, 0, 0);
                    c = __builtin_amdgcn_mfma_f32_16x16x32_bf16(a[mt][1], bh, c, 0, 0, 0);
                    acc[mt][nt4] = c;
                }
            }
        }
        // epilogue: quantized ref-formula score -> packed u64 running min
#pragma unroll
        for (int nt4 = 0; nt4 < 4; ++nt4) {
            const int ncol = ns * 4096 + nt * 128 + (wn * 4 + nt4) * 16 + li;
            const float sev = se[ncol];
#pragma unroll
            for (int mt = 0; mt < 2; ++mt) {
                f32x4 c = acc[mt][nt4];
#pragma unroll
                for (int r = 0; r < 4; ++r) {
                    float s = fmaf(-2.f, c[r], __fadd_rn(szr[mt * 4 + r], sev));
                    ull k = ((ull)__float_as_uint(s) << 32) | (unsigned)ncol;
                    int sl = mt * 4 + r;
                    if (k < key[sl]) key[sl] = k;
                }
            }
        }
        if (nt & 1) {                         // flush superchunk (2 nt = 128 cols/wave)
            int sc = nt >> 1;
#pragma unroll
            for (int sl = 0; sl < 8; ++sl) {
                ull kk = key[sl];
#pragma unroll
                for (int off = 1; off <= 8; off <<= 1) {
                    ull o = __shfl_xor(kk, off, 64);
                    if (o < kk) kk = o;
                }
                if (li == 0) {
                    int row = (mb << 6) + (wm << 5) + ((sl >> 2) << 4) + (quad << 2) + (sl & 3);
                    minima[(size_t)row * 64 + ((ns * 16 + sc) * 2 + wn)] = kk;
                }
                key[sl] = ~0ULL;
            }
        }
    }
}

// ---------------- pass2: top-4 of 64 cells + fp64 fixup + idx out ----------------
// grid 1024, block 256; block owns 16 consecutive rows (z tile staged in LDS).
__global__ __launch_bounds__(256) void vq_pick2(
        const float* __restrict__ z, const float* __restrict__ emb,
        const float* __restrict__ ws, const ull* __restrict__ minima,
        float* __restrict__ out) {
    __shared__ float Lz[256 * 17];            // [c][t0..15], padded
    const float* sz = ws + WS_SZ;
    const float* se = ws + WS_SE;
    const int tid = threadIdx.x;
    const int w = tid >> 6, lane = tid & 63, li = lane & 15;
    const int m0 = blockIdx.x * 16;
    const int b = m0 >> 10, t0 = m0 & (T_ - 1);

    {   // stage z tile: 16 t x 256 c
        const float* src = z + (size_t)b * C_ * T_ + (size_t)tid * T_ + t0;
#pragma unroll
        for (int u = 0; u < 4; ++u) {
            float4 v = *(const float4*)(src + u * 4);
            Lz[tid * 17 + u * 4 + 0] = v.x;
            Lz[tid * 17 + u * 4 + 1] = v.y;
            Lz[tid * 17 + u * 4 + 2] = v.z;
            Lz[tid * 17 + u * 4 + 3] = v.w;
        }
    }
    __syncthreads();

    for (int rr = 0; rr < 4; ++rr) {
        const int tloc = w * 4 + rr;
        const int m = m0 + tloc;
        // top-4 of the 64 jittered cell-minima
        ull kmin = minima[(size_t)m * 64 + lane];
        int cand[4];
#pragma unroll
        for (int rep = 0; rep < 4; ++rep) {
            ull bf = kmin;
#pragma unroll
            for (int off = 1; off <= 32; off <<= 1) {
                ull o = __shfl_xor(bf, off, 64);
                if (o < bf) bf = o;
            }
            int ix = (int)(unsigned)(bf & 0xFFFFFFFFull);
            cand[rep] = ix < 0 ? 0 : (ix > N_ - 1 ? N_ - 1 : ix);
            if (kmin == bf) kmin = ~0ULL;
        }
        // fp64 dots: 4 groups of 16 lanes, one candidate each
        const int cn = cand[lane >> 4];
        const float* ep = emb + (size_t)cn * C_;
        double sum = 0.0;
#pragma unroll
        for (int cc = 0; cc < 16; ++cc) {
            int c = cc * 16 + li;
            sum = fma((double)Lz[c * 17 + tloc], (double)ep[c], sum);
        }
#pragma unroll
        for (int off = 1; off <= 8; off <<= 1)
            sum += __shfl_xor(sum, off, 64);
        double s0 = __shfl(sum, 0, 64), s1 = __shfl(sum, 16, 64);
        double s2 = __shfl(sum, 32, 64), s3 = __shfl(sum, 48, 64);
        if (lane == 0) {
            float szm = sz[m];
            float d0 = fmaf(-2.f, (float)s0, __fadd_rn(szm, se[cand[0]]));
            float d1 = fmaf(-2.f, (float)s1, __fadd_rn(szm, se[cand[1]]));
            float d2 = fmaf(-2.f, (float)s2, __fadd_rn(szm, se[cand[2]]));
            float d3 = fmaf(-2.f, (float)s3, __fadd_rn(szm, se[cand[3]]));
            float bd = d0; int bi = cand[0];
            if (d1 < bd || (d1 == bd && cand[1] < bi)) { bd = d1; bi = cand[1]; }
            if (d2 < bd || (d2 == bd && cand[2] < bi)) { bd = d2; bi = cand[2]; }
            if (d3 < bd || (d3 == bd && cand[3] < bi)) { bd = d3; bi = cand[3]; }
            out[OUT_IDX + m] = (float)bi;
        }
    }
}

// ---------------- fallback round-5 pass1/pass2 (known-PASS) ----------------
__global__ __launch_bounds__(256) void vq_pass1_fp32(
        const float* __restrict__ z,
        const float* __restrict__ emb,
        float* __restrict__ ws) {
    __shared__ float As[32][68];
    __shared__ float Bs[32][68];
    const float* s_z = ws + WS_SZ;
    const float* s_e = ws + WS_SE;
    int* i1ws = (int*)ws + O_I1;
    int* i2ws = (int*)ws + O_I2;
    const int tid = threadIdx.x;
    const int mt  = blockIdx.x;
    const int tx  = tid & 15, ty = tid >> 4;
    const int b   = mt >> 4;
    const int t0  = (mt << 6) & (T_ - 1);
    const float* zbase = z + (size_t)b * C_ * T_ + t0;
    const int a_k = tid >> 4;
    const int a_m = (tid & 15) << 2;
    const int b_j = tid >> 2;
    const int b_q = (tid & 3) << 3;
    const float4 sz4 = *(const float4*)(s_z + mt * 64 + (ty << 2));
    const float szv[4] = {sz4.x, sz4.y, sz4.z, sz4.w};
    float v1[4], v2[4];
    int   i1[4], i2[4];
#pragma unroll
    for (int i = 0; i < 4; ++i) {
        v1[i] = INFINITY; v2[i] = INFINITY;
        i1[i] = 0x7FFFFFFF; i2[i] = 0x7FFFFFFF;
    }
    for (int nt = 0; nt < N_ / 64; ++nt) {
        const int n0 = nt * 64;
        float acc[4][4];
#pragma unroll
        for (int i = 0; i < 4; ++i)
#pragma unroll
            for (int j = 0; j < 4; ++j) acc[i][j] = 0.f;
        for (int kt = 0; kt < C_; kt += 32) {
            __syncthreads();
#pragma unroll
            for (int p = 0; p < 2; ++p) {
                int k = a_k + p * 16;
                float4 af = *(const float4*)(zbase + (size_t)(kt + k) * T_ + a_m);
                *(float4*)&As[k][a_m] = af;
            }
            {
                const float* ep = emb + (size_t)(n0 + b_j) * C_ + kt + b_q;
                float4 e0 = ((const float4*)ep)[0];
                float4 e1 = ((const float4*)ep)[1];
                Bs[b_q + 0][b_j] = e0.x; Bs[b_q + 1][b_j] = e0.y;
                Bs[b_q + 2][b_j] = e0.z; Bs[b_q + 3][b_j] = e0.w;
                Bs[b_q + 4][b_j] = e1.x; Bs[b_q + 5][b_j] = e1.y;
                Bs[b_q + 6][b_j] = e1.z; Bs[b_q + 7][b_j] = e1.w;
            }
            __syncthreads();
#pragma unroll
            for (int k = 0; k < 32; ++k) {
                const float4 a  = *(const float4*)&As[k][ty << 2];
                const float4 bv = *(const float4*)&Bs[k][tx << 2];
                acc[0][0] = fmaf(a.x, bv.x, acc[0][0]);
                acc[0][1] = fmaf(a.x, bv.y, acc[0][1]);
                acc[0][2] = fmaf(a.x, bv.z, acc[0][2]);
                acc[0][3] = fmaf(a.x, bv.w, acc[0][3]);
                acc[1][0] = fmaf(a.y, bv.x, acc[1][0]);
                acc[1][1] = fmaf(a.y, bv.y, acc[1][1]);
                acc[1][2] = fmaf(a.y, bv.z, acc[1][2]);
                acc[1][3] = fmaf(a.y, bv.w, acc[1][3]);
                acc[2][0] = fmaf(a.z, bv.x, acc[2][0]);
                acc[2][1] = fmaf(a.z, bv.y, acc[2][1]);
                acc[2][2] = fmaf(a.z, bv.z, acc[2][2]);
                acc[2][3] = fmaf(a.z, bv.w, acc[2][3]);
                acc[3][0] = fmaf(a.w, bv.x, acc[3][0]);
                acc[3][1] = fmaf(a.w, bv.y, acc[3][1]);
                acc[3][2] = fmaf(a.w, bv.z, acc[3][2]);
                acc[3][3] = fmaf(a.w, bv.w, acc[3][3]);
            }
        }
        const float4 se4 = *(const float4*)(s_e + n0 + (tx << 2));
        const float sev[4] = {se4.x, se4.y, se4.z, se4.w};
#pragma unroll
        for (int j = 0; j < 4; ++j) {
            const int n = n0 + (tx << 2) + j;
#pragma unroll
            for (int i = 0; i < 4; ++i) {
                float A = __fadd_rn(szv[i], sev[j]);
                float s = fmaf(-2.f, acc[i][j], A);
                if (s < v1[i]) { v2[i] = v1[i]; i2[i] = i1[i]; v1[i] = s; i1[i] = n; }
                else if (s < v2[i]) { v2[i] = s; i2[i] = n; }
            }
        }
    }
#pragma unroll
    for (int i = 0; i < 4; ++i) {
        float a1 = v1[i], a2 = v2[i];
        int   y1 = i1[i], y2 = i2[i];
#pragma unroll
        for (int off = 8; off >= 1; off >>= 1) {
            float o1 = __shfl_xor(a1, off, 64); int p1 = __shfl_xor(y1, off, 64);
            float o2 = __shfl_xor(a2, off, 64); int p2 = __shfl_xor(y2, off, 64);
            bool alt = (o1 < a1) || (o1 == a1 && p1 < y1);
            float w1 = alt ? o1 : a1; int q1 = alt ? p1 : y1;
            float lv = alt ? a1 : o1; int lq = alt ? y1 : p1;
            float wv = alt ? o2 : a2; int wq = alt ? p2 : y2;
            bool sb = (lv < wv) || (lv == wv && lq < wq);
            a2 = sb ? lv : wv; y2 = sb ? lq : wq;
            a1 = w1; y1 = q1;
        }
        if (tx == 0) {
            int m = mt * 64 + (ty << 2) + i;
            i1ws[m] = y1;
            i2ws[m] = y2;
        }
    }
}

__global__ __launch_bounds__(256) void vq_pass2_fp32(
        const float* __restrict__ z,
        const float* __restrict__ emb,
        float* __restrict__ ws,
        float* __restrict__ out) {
    const float* s_z = ws + WS_SZ;
    const float* s_e = ws + WS_SE;
    const int* i1ws = (const int*)ws + O_I1;
    const int* i2ws = (const int*)ws + O_I2;
    const int tid  = threadIdx.x;
    const int wave = tid >> 6, lane = tid & 63;
    const int half = lane >> 5;
    const int c0   = (lane & 31) << 3;
    const int rowbase = (blockIdx.x * 4 + wave) * 64;
    for (int r = 0; r < 64; ++r) {
        const int m = rowbase + r;
        int c1 = i1ws[m], c2 = i2ws[m];
        c1 = c1 < 0 ? 0 : (c1 > N_ - 1 ? N_ - 1 : c1);
        c2 = c2 < 0 ? 0 : (c2 > N_ - 1 ? N_ - 1 : c2);
        const int b = m >> 10, t = m & (T_ - 1);
        const float* zp = z + (size_t)b * C_ * T_ + t;
        const int cand = half ? c2 : c1;
        const float* ep = emb + (size_t)cand * C_;
        double sum = 0.0;
#pragma unroll
        for (int c = 0; c < 8; ++c)
            sum = fma((double)zp[(size_t)(c0 + c) * T_], (double)ep[c0 + c], sum);
#pragma unroll
        for (int off = 1; off <= 16; off <<= 1)
            sum += __shfl_xor(sum, off, 64);
        double s1 = __shfl(sum, 0, 64);
        double s2 = __shfl(sum, 32, 64);
        if (lane == 0) {
            float p1 = (float)s1, p2 = (float)s2;
            float d1 = fmaf(-2.f, p1, __fadd_rn(s_z[m], s_e[c1]));
            float d2 = fmaf(-2.f, p2, __fadd_rn(s_z[m], s_e[c2]));
            int win = ((d2 < d1) || (d2 == d1 && c2 < c1)) ? c2 : c1;
            out[OUT_IDX + m] = (float)win;
        }
    }
}

// ---------------- gather z_q (transposed) + loss partial; idx from out ----------------
__global__ __launch_bounds__(256) void vq_gather(
        const float* __restrict__ z,
        const float* __restrict__ emb,
        float* __restrict__ partial,
        float* __restrict__ out) {
    __shared__ float Ls[64][129];
    __shared__ int   idxs[64];
    __shared__ float wred[4];
    const int tid = threadIdx.x;
    const int mg  = blockIdx.x;
    const int m0  = mg << 6;
    const int b   = m0 >> 10;
    const int t0  = m0 & (T_ - 1);
    if (tid < 64) {
        int ix = (int)out[OUT_IDX + m0 + tid];
        idxs[tid] = ix < 0 ? 0 : (ix > N_ - 1 ? N_ - 1 : ix);
    }
    __syncthreads();
    float lsum = 0.f;
    const int w = tid >> 6, l = tid & 63;
    const int tt2 = tid & 63, c0 = tid >> 6;
    const size_t base = (size_t)b * (C_ * T_) + t0 + tt2;
#pragma unroll
    for (int ch = 0; ch < 2; ++ch) {
        __syncthreads();
#pragma unroll
        for (int it = 0; it < 8; ++it) {
            int tt = it * 8 + w * 2 + (l >> 5);
            int cq = l & 31;
            int row = idxs[tt];
            float4 ev = *(const float4*)(emb + (size_t)row * C_ + ch * 128 + (cq << 2));
            Ls[tt][(cq << 2) + 0] = ev.x;
            Ls[tt][(cq << 2) + 1] = ev.y;
            Ls[tt][(cq << 2) + 2] = ev.z;
            Ls[tt][(cq << 2) + 3] = ev.w;
        }
        __syncthreads();
#pragma unroll
        for (int st = 0; st < 32; ++st) {
            int c_l = (st << 2) + c0;
            int c   = (ch << 7) + c_l;
            float v = Ls[tt2][c_l];
            size_t off = base + (size_t)c * T_;
            out[OUT_ZQ + off] = v;
            float d = v - z[off];
            lsum = fmaf(d, d, lsum);
        }
    }
#pragma unroll
    for (int off = 32; off >= 1; off >>= 1) lsum += __shfl_xor(lsum, off, 64);
    if (l == 0) wred[w] = lsum;
    __syncthreads();
    if (tid == 0) partial[mg] = wred[0] + wred[1] + wred[2] + wred[3];
}

__global__ __launch_bounds__(256) void vq_loss(const float* __restrict__ partial,
                                               float* __restrict__ out) {
    __shared__ float wred[4];
    const int tid = threadIdx.x;
    float v = partial[tid];
#pragma unroll
    for (int off = 32; off >= 1; off >>= 1) v += __shfl_xor(v, off, 64);
    if ((tid & 63) == 0) wred[tid >> 6] = v;
    __syncthreads();
    if (tid == 0)
        out[OUT_LOSS] = (wred[0] + wred[1] + wred[2] + wred[3]) * (1.25f / 4194304.f);
}

extern "C" void kernel_launch(void* const* d_in, const int* in_sizes, int n_in,
                              void* d_out, int out_size, void* d_ws, size_t ws_size,
                              hipStream_t stream) {
    const float* z   = (const float*)d_in[0];
    const float* emb = (const float*)d_in[1];
    float* out = (float*)d_out;
    float* ws  = (float*)d_ws;

    vq_sums<<<dim3((M_ + N_) / 256), dim3(256), 0, stream>>>(z, emb, ws);

    if (ws_size >= WS_NEED) {   // fast MFMA path
        char* fb = (char*)d_ws + FB_OFF;
        ull* minima = (ull*)((char*)d_ws + MIN_OFF);
        vq_prep_b<<<dim3(1024), dim3(256), 0, stream>>>(emb, fb);
        vq_mfma2<<<dim3(256, 2), dim3(256), 0, stream>>>(z, fb, ws + WS_SZ, ws + WS_SE, minima);
        vq_pick2<<<dim3(1024), dim3(256), 0, stream>>>(z, emb, ws, minima, out);
        vq_gather<<<dim3(M_ / 64), dim3(256), 0, stream>>>(z, emb, ws + WS_PART, out);
        vq_loss<<<dim3(1), dim3(256), 0, stream>>>(ws + WS_PART, out);
    } else {                    // round-5 fallback (known-PASS)
        vq_pass1_fp32<<<dim3(M_ / 64), dim3(256), 0, stream>>>(z, emb, ws);
        vq_pass2_fp32<<<dim3(64), dim3(256), 0, stream>>>(z, emb, ws, out);
        vq_gather<<<dim3(M_ / 64), dim3(256), 0, stream>>>(z, emb, ws + O_PART, out);
        vq_loss<<<dim3(1), dim3(256), 0, stream>>>(ws + O_PART, out);
    }
}